// Round 2
// baseline (29.260 us; speedup 1.0000x reference)
//
#include <hip/hip_runtime.h>
#include <math.h>

// Problem constants (from setup_inputs): xcorr [32, 3, 64, 4096] fp32, nlag = 2048.
#define NB 32
#define NC 3
#define NX 64
#define NT 4096
#define NGRID 201

__device__ __forceinline__ bool better(float va, int ia, float vb, int ib) {
    // lexicographic: larger value wins; tie -> lower index wins (lax.top_k stability)
    return (va > vb) || (va == vb && ia < ib);
}

// One block per (b, x). Scans the 3 channel rows (4096 lags each) directly from
// global via coalesced float4 loads (no LDS staging), finds top-2 local maxima
// of |xcorr|, does parabolic 201-pt sub-sample refinement, picks the channel
// with max weight, writes the 4 stacked outputs. No workspace, single launch.
__global__ __launch_bounds__(256) void detect_peaks_kernel(
    const float* __restrict__ xcorr,
    const int*   __restrict__ nlag_p,
    float* __restrict__ out)
{
    __shared__ float rv0[4], rv1[4];
    __shared__ int   ri0[4], ri1[4];

    const int bid  = blockIdx.x;          // (b, x)
    const int b    = bid / NX;
    const int x    = bid % NX;
    const int tid  = threadIdx.x;
    const int lane = tid & 63;
    const int wid  = tid >> 6;

    float best_w = -INFINITY, best_s = 0.0f, best_f = 0.0f;

    for (int c = 0; c < NC; ++c) {
        const float* __restrict__ xr =
            xcorr + ((size_t)((b * NC + c) * NX) + x) * NT;

        // ---- per-thread top-2 of masked values (ascending index order) ----
        float v0 = -1.0f, v1 = -1.0f;
        int   i0 = 0x7fffffff, i1 = 0x7fffffff;

        #pragma unroll
        for (int k = 0; k < 4; ++k) {
            const int t4 = (k * 256 + tid) * 4;   // first element of this float4
            const float4 v = *reinterpret_cast<const float4*>(xr + t4);
            const float a0 = fabsf(v.x), a1 = fabsf(v.y);
            const float a2 = fabsf(v.z), a3 = fabsf(v.w);

            // neighbors across float4 boundaries via wave shuffle;
            // wave-edge lanes re-fetch one scalar from global (cache hit)
            float lm = __shfl_up(a3, 1);
            float rm = __shfl_down(a0, 1);
            if (lane == 0)  lm = (t4 > 0)      ? fabsf(xr[t4 - 1]) : -INFINITY;
            if (lane == 63) rm = (t4 + 4 < NT) ? fabsf(xr[t4 + 4]) : -INFINITY;

            // keep = (x == 3-tap max); candidate v = x*keep (zeros stay, like ref)
            const float c0 = (a0 >= lm && a0 >= a1) ? a0 : 0.0f;
            const float c1 = (a1 >= a0 && a1 >= a2) ? a1 : 0.0f;
            const float c2 = (a2 >= a1 && a2 >= a3) ? a2 : 0.0f;
            const float c3 = (a3 >= a2 && a3 >= rm) ? a3 : 0.0f;

            if (c0 > v0)      { v1 = v0; i1 = i0; v0 = c0; i0 = t4;     }
            else if (c0 > v1) { v1 = c0; i1 = t4;                       }
            if (c1 > v0)      { v1 = v0; i1 = i0; v0 = c1; i0 = t4 + 1; }
            else if (c1 > v1) { v1 = c1; i1 = t4 + 1;                   }
            if (c2 > v0)      { v1 = v0; i1 = i0; v0 = c2; i0 = t4 + 2; }
            else if (c2 > v1) { v1 = c2; i1 = t4 + 2;                   }
            if (c3 > v0)      { v1 = v0; i1 = i0; v0 = c3; i0 = t4 + 3; }
            else if (c3 > v1) { v1 = c3; i1 = t4 + 3;                   }
        }

        // ---- wave butterfly top-2 merge ----
        #pragma unroll
        for (int off = 1; off < 64; off <<= 1) {
            const float ov0 = __shfl_xor(v0, off);
            const int   oi0 = __shfl_xor(i0, off);
            const float ov1 = __shfl_xor(v1, off);
            const int   oi1 = __shfl_xor(i1, off);
            if (better(ov0, oi0, v0, i0)) {
                float nv1; int ni1;
                if (better(v0, i0, ov1, oi1)) { nv1 = v0;  ni1 = i0;  }
                else                          { nv1 = ov1; ni1 = oi1; }
                v0 = ov0; i0 = oi0; v1 = nv1; i1 = ni1;
            } else {
                if (better(ov0, oi0, v1, i1)) { v1 = ov0; i1 = oi0; }
            }
        }

        if (lane == 0) { rv0[wid] = v0; ri0[wid] = i0; rv1[wid] = v1; ri1[wid] = i1; }
        __syncthreads();

        // ---- wave 0: merge the 4 wave results, then 201-pt grid argmax ----
        if (tid < 64) {
            float a0 = rv0[0], a1 = rv1[0];
            int   ai0 = ri0[0], ai1 = ri1[0];
            #pragma unroll
            for (int w = 1; w < 4; ++w) {
                const float b0 = rv0[w], b1 = rv1[w];
                const int   bi0 = ri0[w], bi1 = ri1[w];
                if (better(b0, bi0, a0, ai0)) {
                    float nv1; int ni1;
                    if (better(a0, ai0, b1, bi1)) { nv1 = a0; ni1 = ai0; }
                    else                          { nv1 = b1; ni1 = bi1; }
                    a0 = b0; ai0 = bi0; a1 = nv1; ai1 = ni1;
                } else {
                    if (better(b0, bi0, a1, ai1)) { a1 = b0; ai1 = bi0; }
                }
            }

            const float s0 = a0, s1 = a1;
            const int   p0 = ai0;
            const float weight = (0.1f + 3.0f * (s0 - s1)) * (s0 * s0);

            // parabola through clipped neighbors (uniform-address loads, cache hits)
            const int im1 = (p0 - 1 < 0) ? 0 : p0 - 1;
            const int ip1 = (p0 + 1 > NT - 1) ? NT - 1 : p0 + 1;
            const float ym1 = fabsf(xr[im1]);
            const float yc  = fabsf(xr[p0]);
            const float yp1 = fabsf(xr[ip1]);
            const float A = 0.5f * (ym1 + yp1) - yc;
            const float B = 0.5f * (yp1 - ym1);
            const float C = yc;

            // grid argmax over xg = linspace(-1,1,201)
            float bv = -INFINITY; int bi = 0x7fffffff;
            #pragma unroll
            for (int k = 0; k < 4; ++k) {
                const int gi = lane + k * 64;
                if (gi < NGRID) {
                    const float xg = 0.01f * (float)(gi - 100);
                    const float yg = (A * xg + B) * xg + C;
                    if (yg > bv) { bv = yg; bi = gi; }   // strict > = first occurrence
                }
            }
            #pragma unroll
            for (int off = 1; off < 64; off <<= 1) {
                const float ov = __shfl_xor(bv, off);
                const int   oi = __shfl_xor(bi, off);
                if (ov > bv || (ov == bv && oi < bi)) { bv = ov; bi = oi; }
            }

            // channel argmax (ascending c + strict > == first occurrence)
            if (weight > best_w) {
                best_w = weight;
                best_s = bv;
                best_f = (float)p0 + 0.01f * (float)(bi - 100);
            }
        }
        __syncthreads();   // protect rv/ri before next channel's writes
    }

    if (tid == 0) {
        const float nlagf = (float)(*nlag_p);
        const int n = NB * NX;
        const int o = b * NX + x;
        const float shift_idx = best_f - nlagf;
        out[0 * n + o] = best_s;              // max_cc (interpolated score)
        out[1 * n + o] = best_w;              // weight
        out[2 * n + o] = shift_idx / 100.0f;  // shift_t (SAMPLING_RATE = 100)
        out[3 * n + o] = shift_idx;           // shift_idx
    }
}

extern "C" void kernel_launch(void* const* d_in, const int* in_sizes, int n_in,
                              void* d_out, int out_size, void* d_ws, size_t ws_size,
                              hipStream_t stream) {
    const float* xcorr  = (const float*)d_in[0];
    const int*   nlag_p = (const int*)d_in[1];
    float* out = (float*)d_out;

    detect_peaks_kernel<<<NB * NX, 256, 0, stream>>>(xcorr, nlag_p, out);
}